// Round 3
// baseline (1369.373 us; speedup 1.0000x reference)
//
#include <hip/hip_runtime.h>
#include <hip/hip_bf16.h>

#define Bn 32
#define Cc 128
#define Nn 307
#define Ll 12
#define LH 13
#define LAYERS 4
#define BN_EPS 1e-5f

// ---- G1[l][b,t0,n] = sum_c seq0[b,c,n,t0]*c1_l[c], all 4 layers in one pass ----
// seq0 is X (layout [B,C,N,12]); for pad=1 the logical t0=0 plane is zero.
__global__ __launch_bounds__(256) void k_g1(const float* __restrict__ X,
                                            const float* __restrict__ c1,
                                            float* __restrict__ G1, int T, int pad) {
    __shared__ float s_c1[LAYERS * Cc];
    for (int j = threadIdx.x; j < LAYERS * Cc; j += blockDim.x) s_c1[j] = c1[j];
    __syncthreads();
    int i = blockIdx.x * blockDim.x + threadIdx.x;
    int total = Bn * Nn * T;
    if (i >= total) return;
    int t0 = i % T;
    int bn = i / T;
    int n = bn % Nn;
    int b = bn / Nn;
    float a0 = 0.f, a1 = 0.f, a2 = 0.f, a3 = 0.f;
    int tsrc = t0 - pad;
    if (tsrc >= 0) {
        const float* p = X + ((size_t)b * Cc * Nn + n) * Ll + tsrc;
        for (int c = 0; c < Cc; ++c) {
            float vx = p[(size_t)c * Nn * Ll];
            a0 += vx * s_c1[0 * Cc + c];
            a1 += vx * s_c1[1 * Cc + c];
            a2 += vx * s_c1[2 * Cc + c];
            a3 += vx * s_c1[3 * Cc + c];
        }
    }
    size_t stride = (size_t)Bn * T * Nn;
    size_t base = ((size_t)b * T + t0) * Nn + n;
    G1[base] = a0;
    G1[base + stride] = a1;
    G1[base + 2 * stride] = a2;
    G1[base + 3 * stride] = a3;
}

// ---- G2[l][b,t0,c] = sum_n seq0[b,c,n,t0]*c2_l[n], all 4 layers in one pass ----
__global__ __launch_bounds__(256) void k_g2(const float* __restrict__ X,
                                            const float* __restrict__ c2,
                                            float* __restrict__ G2, int T, int pad) {
    __shared__ float s_c2[LAYERS * Nn];
    for (int j = threadIdx.x; j < LAYERS * Nn; j += blockDim.x) s_c2[j] = c2[j];
    __syncthreads();
    int i = blockIdx.x * blockDim.x + threadIdx.x;
    int total = Bn * Cc * T;
    if (i >= total) return;
    int t0 = i % T;
    int bc = i / T;
    int c = bc % Cc;
    int b = bc / Cc;
    float a0 = 0.f, a1 = 0.f, a2 = 0.f, a3 = 0.f;
    int tsrc = t0 - pad;
    if (tsrc >= 0) {
        const float* p = X + ((size_t)(b * Cc + c) * Nn) * Ll + tsrc;
        for (int n = 0; n < Nn; ++n) {
            float vx = p[(size_t)n * Ll];
            a0 += vx * s_c2[0 * Nn + n];
            a1 += vx * s_c2[1 * Nn + n];
            a2 += vx * s_c2[2 * Nn + n];
            a3 += vx * s_c2[3 * Nn + n];
        }
    }
    size_t stride = (size_t)Bn * T * Cc;
    size_t base = ((size_t)b * T + t0) * Cc + c;
    G2[base] = a0;
    G2[base + stride] = a1;
    G2[base + 2 * stride] = a2;
    G2[base + 3 * stride] = a3;
}

// ---- P := identity per batch ----
__global__ __launch_bounds__(256) void k_init(float* __restrict__ P, int T) {
    int i = blockIdx.x * blockDim.x + threadIdx.x;
    if (i >= Bn * T * T) return;
    int r = i % (T * T);
    P[i] = (r / T == r % T) ? 1.f : 0.f;
}

// ---- per-batch attention math: f1,f2 (via P), f1w, scores, logits ----
__global__ __launch_bounds__(256) void k_layer_a(const float* __restrict__ G1l,
                                                 const float* __restrict__ G2l,
                                                 const float* __restrict__ w,
                                                 const float* __restrict__ bb,
                                                 const float* __restrict__ v,
                                                 const float* __restrict__ P,
                                                 float* __restrict__ logits, int T) {
    __shared__ float s_P[LH * LH];
    __shared__ float s_f1[LH * Nn];
    __shared__ float s_f2[LH * Cc];
    __shared__ float s_f1w[LH * Cc];
    __shared__ float s_sc[LH * LH];
    int b = blockIdx.x;
    int tid = threadIdx.x;
    for (int i = tid; i < T * T; i += blockDim.x) s_P[i] = P[b * T * T + i];
    __syncthreads();
    for (int i = tid; i < T * Nn; i += blockDim.x) {
        int t = i / Nn, n = i % Nn;
        float acc = 0.f;
        for (int t0 = 0; t0 < T; ++t0) acc += G1l[((size_t)b * T + t0) * Nn + n] * s_P[t0 * T + t];
        s_f1[i] = acc;
    }
    for (int i = tid; i < T * Cc; i += blockDim.x) {
        int t = i / Cc, c = i % Cc;
        float acc = 0.f;
        for (int t0 = 0; t0 < T; ++t0) acc += G2l[((size_t)b * T + t0) * Cc + c] * s_P[t0 * T + t];
        s_f2[i] = acc;
    }
    __syncthreads();
    for (int i = tid; i < T * Cc; i += blockDim.x) {
        int t = i / Cc, c = i % Cc;
        float acc = 0.f;
        for (int n = 0; n < Nn; ++n) acc += s_f1[t * Nn + n] * w[n * Cc + c];
        s_f1w[i] = acc;
    }
    __syncthreads();
    for (int i = tid; i < T * T; i += blockDim.x) {
        int t = i / T, q = i % T;
        float acc = bb[i];
        for (int c = 0; c < Cc; ++c) acc += s_f1w[t * Cc + c] * s_f2[q * Cc + c];
        s_sc[i] = 1.f / (1.f + expf(-acc));
    }
    __syncthreads();
    for (int i = tid; i < T * T; i += blockDim.x) {
        int t = i / T, q = i % T;
        float acc = 0.f;
        for (int k = 0; k < T; ++k) acc += v[t * T + k] * s_sc[k * T + q];
        logits[b * T * T + i] = acc;
    }
}

// ---- single block: BN(train stats) + softmax -> Co; P_new = P_old * Co^T ----
__global__ __launch_bounds__(256) void k_layer_b(const float* __restrict__ logits,
                                                 const float* __restrict__ g,
                                                 const float* __restrict__ beta,
                                                 const float* __restrict__ Pold,
                                                 float* __restrict__ Pnew, int T) {
    __shared__ float s_log[Bn * LH * LH];
    __shared__ float s_co[Bn * LH * LH];
    __shared__ float s_mean[LH], s_scale[LH], s_shift[LH];
    int tid = threadIdx.x;
    int tot = Bn * T * T;
    for (int i = tid; i < tot; i += blockDim.x) s_log[i] = logits[i];
    __syncthreads();
    if (tid < T) {
        int q = tid;
        int rows = Bn * T;
        float sum = 0.f;
        for (int r = 0; r < rows; ++r) sum += s_log[r * T + q];
        float m = sum / rows;
        float var = 0.f;
        for (int r = 0; r < rows; ++r) {
            float d = s_log[r * T + q] - m;
            var += d * d;
        }
        var /= rows;
        s_mean[q] = m;
        s_scale[q] = rsqrtf(var + BN_EPS) * g[q];
        s_shift[q] = beta[q];
    }
    __syncthreads();
    for (int r = tid; r < Bn * T; r += blockDim.x) {
        float vals[LH];
        float mx = -1e30f;
        for (int q = 0; q < T; ++q) {
            float x = (s_log[r * T + q] - s_mean[q]) * s_scale[q] + s_shift[q];
            vals[q] = x;
            mx = fmaxf(mx, x);
        }
        float sm = 0.f;
        for (int q = 0; q < T; ++q) {
            vals[q] = expf(vals[q] - mx);
            sm += vals[q];
        }
        float inv = 1.f / sm;
        for (int q = 0; q < T; ++q) s_co[r * T + q] = vals[q] * inv;
    }
    __syncthreads();
    // Pnew[b][t0][q] = sum_t Pold[b][t0][t] * Co[b][q][t]
    for (int i = tid; i < tot; i += blockDim.x) {
        int b = i / (T * T);
        int r2 = i % (T * T);
        int t0 = r2 / T, q = r2 % T;
        float acc = 0.f;
        for (int t = 0; t < T; ++t)
            acc += Pold[b * T * T + t0 * T + t] * s_co[(b * T + q) * T + t];
        Pnew[i] = acc;
    }
}

// ---- final: residuals + alpha blend using last column of each channel's P ----
__global__ __launch_bounds__(256) void k_final(const float* __restrict__ XL,
                                               const float* __restrict__ XH,
                                               const float* __restrict__ PL,
                                               const float* __restrict__ PH,
                                               const float* __restrict__ alpha,
                                               float* __restrict__ out) {
    __shared__ float s_pl[Ll];
    __shared__ float s_ph[LH];
    int b = blockIdx.y;
    int tid = threadIdx.x;
    if (tid < Ll) s_pl[tid] = PL[b * Ll * Ll + tid * Ll + (Ll - 1)];
    if (tid < LH) s_ph[tid] = PH[b * LH * LH + tid * LH + (LH - 1)];
    __syncthreads();
    int cn = blockIdx.x * blockDim.x + tid;
    if (cn >= Cc * Nn) return;
    size_t idx = (size_t)b * Cc * Nn + cn;
    const float* pl = XL + idx * Ll;
    const float* ph = XH + idx * Ll;
    float accL = 0.f, accH = 0.f;
    for (int t = 0; t < Ll; ++t) {
        accL += pl[t] * s_pl[t];
        accH += ph[t] * s_ph[t + 1];  // high channel t0=0 plane is zero
    }
    float a = 1.f / (1.f + expf(-alpha[0]));
    float xl = pl[Ll - 1] + accL;
    float xh = ph[Ll - 1] + accH;
    out[idx] = a * xl + (1.f - a) * xh;
}

extern "C" void kernel_launch(void* const* d_in, const int* in_sizes, int n_in,
                              void* d_out, int out_size, void* d_ws, size_t ws_size,
                              hipStream_t stream) {
    const float* XL = (const float*)d_in[0];
    const float* XH = (const float*)d_in[1];
    const float* lc1 = (const float*)d_in[2];
    const float* lc2 = (const float*)d_in[3];
    const float* lw = (const float*)d_in[4];
    const float* lb = (const float*)d_in[5];
    const float* lv = (const float*)d_in[6];
    const float* lg = (const float*)d_in[7];
    const float* lbeta = (const float*)d_in[8];
    const float* hc1 = (const float*)d_in[9];
    const float* hc2 = (const float*)d_in[10];
    const float* hw = (const float*)d_in[11];
    const float* hb = (const float*)d_in[12];
    const float* hv = (const float*)d_in[13];
    const float* hg = (const float*)d_in[14];
    const float* hbeta = (const float*)d_in[15];
    const float* alpha = (const float*)d_in[16];
    float* out = (float*)d_out;

    float* ws = (float*)d_ws;
    float* G1 = ws;                                    // 4*Bn*LH*Nn = 510,848
    float* G2 = G1 + (size_t)LAYERS * Bn * LH * Nn;    // 4*Bn*LH*Cc = 212,992
    float* PaL = G2 + (size_t)LAYERS * Bn * LH * Cc;   // Bn*LH*LH = 5408 each
    float* PbL = PaL + Bn * LH * LH;
    float* PaH = PbL + Bn * LH * LH;
    float* PbH = PaH + Bn * LH * LH;
    float* logits = PbH + Bn * LH * LH;
    // total ~745k floats ~= 3 MB

    // ---------- LOW channel (T = 12, no pad) ----------
    {
        const int T = Ll;
        k_g1<<<(Bn * Nn * T + 255) / 256, 256, 0, stream>>>(XL, lc1, G1, T, 0);
        k_g2<<<(Bn * Cc * T + 255) / 256, 256, 0, stream>>>(XL, lc2, G2, T, 0);
        k_init<<<(Bn * T * T + 255) / 256, 256, 0, stream>>>(PaL, T);
        float* Pc = PaL;
        float* Pn = PbL;
        for (int l = 0; l < LAYERS; ++l) {
            k_layer_a<<<Bn, 256, 0, stream>>>(G1 + (size_t)l * Bn * T * Nn,
                                              G2 + (size_t)l * Bn * T * Cc,
                                              lw + (size_t)l * Nn * Cc, lb + l * T * T,
                                              lv + l * T * T, Pc, logits, T);
            k_layer_b<<<1, 256, 0, stream>>>(logits, lg + l * T, lbeta + l * T, Pc, Pn, T);
            float* tmp = Pc; Pc = Pn; Pn = tmp;
        }
        // final P back in PaL after 4 swaps
    }

    // ---------- HIGH channel (T = 13, left-pad) ----------
    {
        const int T = LH;
        k_g1<<<(Bn * Nn * T + 255) / 256, 256, 0, stream>>>(XH, hc1, G1, T, 1);
        k_g2<<<(Bn * Cc * T + 255) / 256, 256, 0, stream>>>(XH, hc2, G2, T, 1);
        k_init<<<(Bn * T * T + 255) / 256, 256, 0, stream>>>(PaH, T);
        float* Pc = PaH;
        float* Pn = PbH;
        for (int l = 0; l < LAYERS; ++l) {
            k_layer_a<<<Bn, 256, 0, stream>>>(G1 + (size_t)l * Bn * T * Nn,
                                              G2 + (size_t)l * Bn * T * Cc,
                                              hw + (size_t)l * Nn * Cc, hb + l * T * T,
                                              hv + l * T * T, Pc, logits, T);
            k_layer_b<<<1, 256, 0, stream>>>(logits, hg + l * T, hbeta + l * T, Pc, Pn, T);
            float* tmp = Pc; Pc = Pn; Pn = tmp;
        }
        // final P back in PaH
    }

    k_final<<<dim3((Cc * Nn + 255) / 256, Bn), 256, 0, stream>>>(XL, XH, PaL, PaH, alpha, out);
}

// Round 5
// 374.119 us; speedup vs baseline: 3.6603x; 3.6603x over previous
//
#include <hip/hip_runtime.h>

#define Bn 32
#define Cc 128
#define Nn 307
#define Ll 12
#define LH 13
#define LAYERS 4
#define BN_EPS 1e-5f
#define SCW (Cc + 1)  // padded LDS stride to kill bank conflicts

#define NB1 499  // ceil(32*307*13 / 256)
#define NB2 208  // 32*128*13 / 256

// ---- one pass kind-of over X: G1[l][b,t0,n] = sum_c X*c1_l ; G2[l][b,t0,c] = sum_n X*c2_l
// G1 layout: [((ch*4+l)*Bn + b)*13*Nn + t0*Nn + n]; G2: [((ch*4+l)*Bn + b)*13*Cc + t0*Cc + c]
// low: T=12 pad=0 ; high: T=13 pad=1 (t0=0 logical zero plane -> skip, gwm zero-fills)
__global__ __launch_bounds__(256) void k_g12(const float* __restrict__ XL,
                                             const float* __restrict__ XH,
                                             const float* __restrict__ lc1,
                                             const float* __restrict__ hc1,
                                             const float* __restrict__ lc2,
                                             const float* __restrict__ hc2,
                                             float* __restrict__ G1,
                                             float* __restrict__ G2) {
    __shared__ float s_c1[LAYERS * Cc];
    __shared__ float s_c2[LAYERS * Nn];
    int blk = blockIdx.x;
    int tid = threadIdx.x;
    if (blk < 2 * NB1) {
        // ---- G1 part ----
        int ch = blk / NB1;
        const float* X = ch ? XH : XL;
        const float* c1 = ch ? hc1 : lc1;
        int T = ch ? LH : Ll;
        int pad = ch ? 1 : 0;
        for (int j = tid; j < LAYERS * Cc; j += 256) s_c1[j] = c1[j];
        __syncthreads();
        int idx = (blk % NB1) * 256 + tid;
        if (idx >= Bn * Nn * LH) return;
        int t0 = idx % LH;
        int n = (idx / LH) % Nn;
        int b = idx / (LH * Nn);
        if (t0 >= T) return;
        int tsrc = t0 - pad;
        float a0 = 0.f, a1 = 0.f, a2 = 0.f, a3 = 0.f;
        if (tsrc >= 0) {
            const float* p = X + ((size_t)b * Cc * Nn + n) * Ll + tsrc;
            for (int c = 0; c < Cc; ++c) {
                float vx = p[(size_t)c * Nn * Ll];
                a0 += vx * s_c1[0 * Cc + c];
                a1 += vx * s_c1[1 * Cc + c];
                a2 += vx * s_c1[2 * Cc + c];
                a3 += vx * s_c1[3 * Cc + c];
            }
        }
        size_t lstride = (size_t)Bn * LH * Nn;
        size_t base = ((size_t)(ch * LAYERS * Bn + b)) * (LH * Nn) + (size_t)t0 * Nn + n;
        G1[base] = a0;
        G1[base + lstride] = a1;
        G1[base + 2 * lstride] = a2;
        G1[base + 3 * lstride] = a3;
    } else {
        // ---- G2 part ----
        int b2 = blk - 2 * NB1;
        int ch = b2 / NB2;
        const float* X = ch ? XH : XL;
        const float* c2 = ch ? hc2 : lc2;
        int T = ch ? LH : Ll;
        int pad = ch ? 1 : 0;
        for (int j = tid; j < LAYERS * Nn; j += 256) s_c2[j] = c2[j];
        __syncthreads();
        int idx = (b2 % NB2) * 256 + tid;
        int t0 = idx % LH;
        int c = (idx / LH) % Cc;
        int b = idx / (LH * Cc);
        if (t0 >= T) return;
        int tsrc = t0 - pad;
        float a0 = 0.f, a1 = 0.f, a2 = 0.f, a3 = 0.f;
        if (tsrc >= 0) {
            const float* p = X + ((size_t)(b * Cc + c) * Nn) * Ll + tsrc;
            for (int n = 0; n < Nn; ++n) {
                float vx = p[(size_t)n * Ll];
                a0 += vx * s_c2[0 * Nn + n];
                a1 += vx * s_c2[1 * Nn + n];
                a2 += vx * s_c2[2 * Nn + n];
                a3 += vx * s_c2[3 * Nn + n];
            }
        }
        size_t lstride = (size_t)Bn * LH * Cc;
        size_t base = ((size_t)(ch * LAYERS * Bn + b)) * (LH * Cc) + (size_t)t0 * Cc + c;
        G2[base] = a0;
        G2[base + lstride] = a1;
        G2[base + 2 * lstride] = a2;
        G2[base + 3 * lstride] = a3;
    }
}

// ---- per (ch,l,b): GW = G1*w in registers/LDS, then M[t0][t1] = sum_c GW*G2 -> global ----
// grid: 2*LAYERS*Bn = 256 blocks, 256 threads (c x 2 n-halves)
__global__ __launch_bounds__(256) void k_gwm(const float* __restrict__ lw,
                                             const float* __restrict__ hw,
                                             const float* __restrict__ G1,
                                             const float* __restrict__ G2,
                                             float* __restrict__ M) {
    __shared__ float sG1[LH * Nn];
    __shared__ float sAcc[2][LH * SCW];
    __shared__ float sG2[LH * SCW];
    int blk = blockIdx.x;  // (ch*LAYERS + l)*Bn + b
    int cl = blk / Bn;
    int l = cl % LAYERS;
    int ch = cl / LAYERS;
    int T = ch ? LH : Ll;
    const float* w = (ch ? hw : lw) + (size_t)l * Nn * Cc;
    const float* g1 = G1 + (size_t)blk * (LH * Nn);
    const float* g2 = G2 + (size_t)blk * (LH * Cc);
    int tid = threadIdx.x;
    for (int i = tid; i < LH * Nn; i += 256) sG1[i] = (i < T * Nn) ? g1[i] : 0.f;
    for (int i = tid; i < T * Cc; i += 256) sG2[(i / Cc) * SCW + (i % Cc)] = g2[i];
    __syncthreads();
    int half = tid >> 7;
    int c = tid & 127;
    float acc[LH];
#pragma unroll
    for (int t = 0; t < LH; ++t) acc[t] = 0.f;
    int n0 = half ? (Nn / 2) : 0;
    int n1 = half ? Nn : (Nn / 2);
    for (int n = n0; n < n1; ++n) {
        float wv = w[(size_t)n * Cc + c];
#pragma unroll
        for (int t = 0; t < LH; ++t) acc[t] += sG1[t * Nn + n] * wv;
    }
#pragma unroll
    for (int t = 0; t < LH; ++t) sAcc[half][t * SCW + c] = acc[t];
    __syncthreads();
    for (int i = tid; i < LH * Cc; i += 256) {
        int t = i / Cc, cc = i % Cc;
        sAcc[0][t * SCW + cc] += sAcc[1][t * SCW + cc];
    }
    __syncthreads();
    float* Mo = M + (size_t)blk * (LH * LH);
    for (int i = tid; i < T * T; i += 256) {
        int t0 = i / T, t1 = i % T;
        float a = 0.f;
        for (int cc = 0; cc < Cc; ++cc) a += sAcc[0][t0 * SCW + cc] * sG2[t1 * SCW + cc];
        Mo[t0 * LH + t1] = a;
    }
}

// ---- whole 4-layer chain for one channel per block; P kept in LDS; 3-buffer rotation ----
__global__ __launch_bounds__(1024) void k_chain(const float* __restrict__ M,
                                                const float* __restrict__ lb,
                                                const float* __restrict__ lv,
                                                const float* __restrict__ lg,
                                                const float* __restrict__ lbe,
                                                const float* __restrict__ hb,
                                                const float* __restrict__ hv,
                                                const float* __restrict__ hg,
                                                const float* __restrict__ hbe,
                                                float* __restrict__ Pcol) {
    __shared__ float sbuf[3][Bn * LH * LH];
    __shared__ float sMean[LH], sScale[LH], sShift[LH];
    int ch = blockIdx.x;
    int T = ch ? LH : Ll;
    int TT = T * T;
    const float* bbp = ch ? hb : lb;
    const float* vp = ch ? hv : lv;
    const float* gp = ch ? hg : lg;
    const float* bep = ch ? hbe : lbe;
    int tid = threadIdx.x;
    int ip = 0, ia = 1, ib = 2;
    for (int i = tid; i < Bn * TT; i += 1024) {
        int r = i % TT;
        sbuf[0][i] = (r / T == r % T) ? 1.f : 0.f;
    }
    __syncthreads();
    for (int l = 0; l < LAYERS; ++l) {
        float* P = &sbuf[ip][0];
        float* X1 = &sbuf[ia][0];
        float* X2 = &sbuf[ib][0];
        const float* Ml = M + ((size_t)(ch * LAYERS + l) * Bn) * (LH * LH);
        const float* bbl = bbp + l * TT;
        const float* vl = vp + l * TT;
        // stage M -> X1 (stride 13 preserved)
        for (int i = tid; i < Bn * LH * LH; i += 1024) X1[i] = Ml[i];
        __syncthreads();
        // S1[b][t][t1] = sum_t0 P[b][t0*T+t] * M[b][t0*13+t1]   -> X2
        for (int i = tid; i < Bn * TT; i += 1024) {
            int b = i / TT, r = i % TT, t = r / T, t1 = r % T;
            const float* Pb = P + b * TT;
            const float* Mb = X1 + b * LH * LH;
            float a = 0.f;
            for (int t0 = 0; t0 < T; ++t0) a += Pb[t0 * T + t] * Mb[t0 * LH + t1];
            X2[i] = a;
        }
        __syncthreads();
        // scores[b][t][q] = sigmoid(bb + sum_t1 S1[b][t][t1]*P[b][t1*T+q]) -> X1
        for (int i = tid; i < Bn * TT; i += 1024) {
            int b = i / TT, r = i % TT, t = r / T, q = r % T;
            const float* S1b = X2 + b * TT + t * T;
            const float* Pb = P + b * TT;
            float a = bbl[r];
            for (int t1 = 0; t1 < T; ++t1) a += S1b[t1] * Pb[t1 * T + q];
            X1[i] = 1.f / (1.f + expf(-a));
        }
        __syncthreads();
        // logits[b][t][q] = sum_k v[t][k]*scores[b][k][q] -> X2
        for (int i = tid; i < Bn * TT; i += 1024) {
            int b = i / TT, r = i % TT, t = r / T, q = r % T;
            float a = 0.f;
            for (int k = 0; k < T; ++k) a += vl[t * T + k] * X1[b * TT + k * T + q];
            X2[i] = a;
        }
        __syncthreads();
        // BN partials (per (q,b)) -> X1[0..2*T*Bn) (scores dead)
        if (tid < T * Bn) {
            int b = tid % Bn, q = tid / Bn;
            float s = 0.f, ss = 0.f;
            for (int t = 0; t < T; ++t) {
                float x = X2[b * TT + t * T + q];
                s += x;
                ss += x * x;
            }
            X1[q * Bn + b] = s;
            X1[T * Bn + q * Bn + b] = ss;
        }
        __syncthreads();
        if (tid < T) {
            float s = 0.f, ss = 0.f;
            for (int b = 0; b < Bn; ++b) {
                s += X1[tid * Bn + b];
                ss += X1[T * Bn + tid * Bn + b];
            }
            float inv = 1.f / (float)(Bn * T);
            float m = s * inv;
            float var = ss * inv - m * m;
            sMean[tid] = m;
            sScale[tid] = rsqrtf(var + BN_EPS) * gp[l * T + tid];
            sShift[tid] = bep[l * T + tid];
        }
        __syncthreads();
        // softmax rows (b,t) over q: read logits X2, write Co -> X1
        if (tid < Bn * T) {
            int b = tid / T, t = tid % T;
            float vals[LH];
            float mx = -1e30f;
            for (int q = 0; q < T; ++q) {
                float x = (X2[b * TT + t * T + q] - sMean[q]) * sScale[q] + sShift[q];
                vals[q] = x;
                mx = fmaxf(mx, x);
            }
            float sm = 0.f;
            for (int q = 0; q < T; ++q) {
                vals[q] = expf(vals[q] - mx);
                sm += vals[q];
            }
            float inv = 1.f / sm;
            for (int q = 0; q < T; ++q) X1[b * TT + t * T + q] = vals[q] * inv;
        }
        __syncthreads();
        // P update: Pn[b][t0][q] = sum_t P[b][t0*T+t] * Co[b][q*T+t]  -> X2
        for (int i = tid; i < Bn * TT; i += 1024) {
            int b = i / TT, r = i % TT, t0 = r / T, q = r % T;
            const float* Pb = P + b * TT;
            const float* Cb = X1 + b * TT + q * T;
            float a = 0.f;
            for (int t = 0; t < T; ++t) a += Pb[t0 * T + t] * Cb[t];
            X2[i] = a;
        }
        __syncthreads();
        int tmp = ip; ip = ib; ib = tmp;  // new P is X2; old P becomes scratch
    }
    const float* Pf = &sbuf[ip][0];
    for (int i = tid; i < Bn * T; i += 1024) {
        int b = i / T, t0 = i % T;
        Pcol[ch * Bn * LH + b * LH + t0] = Pf[b * TT + t0 * T + (T - 1)];
    }
}

// ---- final: residuals + alpha blend using last-column weights ----
__global__ __launch_bounds__(256) void k_final(const float* __restrict__ XL,
                                               const float* __restrict__ XH,
                                               const float* __restrict__ Pcol,
                                               const float* __restrict__ alpha,
                                               float* __restrict__ out) {
    __shared__ float s_pl[Ll];
    __shared__ float s_ph[LH];
    int b = blockIdx.y;
    int tid = threadIdx.x;
    if (tid < Ll) s_pl[tid] = Pcol[b * LH + tid];
    if (tid < LH) s_ph[tid] = Pcol[Bn * LH + b * LH + tid];
    __syncthreads();
    int cn = blockIdx.x * blockDim.x + tid;
    if (cn >= Cc * Nn) return;
    size_t idx = (size_t)b * Cc * Nn + cn;
    const float* pl = XL + idx * Ll;
    const float* ph = XH + idx * Ll;
    float accL = 0.f, accH = 0.f;
#pragma unroll
    for (int t = 0; t < Ll; ++t) {
        accL += pl[t] * s_pl[t];
        accH += ph[t] * s_ph[t + 1];  // high-channel t0=0 plane is the zero pad
    }
    float a = 1.f / (1.f + expf(-alpha[0]));
    float xl = pl[Ll - 1] + accL;
    float xh = ph[Ll - 1] + accH;
    out[idx] = a * xl + (1.f - a) * xh;
}

extern "C" void kernel_launch(void* const* d_in, const int* in_sizes, int n_in,
                              void* d_out, int out_size, void* d_ws, size_t ws_size,
                              hipStream_t stream) {
    const float* XL = (const float*)d_in[0];
    const float* XH = (const float*)d_in[1];
    const float* lc1 = (const float*)d_in[2];
    const float* lc2 = (const float*)d_in[3];
    const float* lw = (const float*)d_in[4];
    const float* lb = (const float*)d_in[5];
    const float* lv = (const float*)d_in[6];
    const float* lg = (const float*)d_in[7];
    const float* lbeta = (const float*)d_in[8];
    const float* hc1 = (const float*)d_in[9];
    const float* hc2 = (const float*)d_in[10];
    const float* hw = (const float*)d_in[11];
    const float* hb = (const float*)d_in[12];
    const float* hv = (const float*)d_in[13];
    const float* hg = (const float*)d_in[14];
    const float* hbeta = (const float*)d_in[15];
    const float* alpha = (const float*)d_in[16];
    float* out = (float*)d_out;

    float* ws = (float*)d_ws;
    float* G1 = ws;                                        // 2*4*32*13*307 = 1,021,696
    float* G2 = G1 + (size_t)2 * LAYERS * Bn * LH * Nn;    // 2*4*32*13*128 = 425,984
    float* M = G2 + (size_t)2 * LAYERS * Bn * LH * Cc;     // 2*4*32*169    =  43,264
    float* Pcol = M + (size_t)2 * LAYERS * Bn * LH * LH;   // 2*32*13       =     832
    // total ~1.49M floats ~= 6 MB

    k_g12<<<2 * NB1 + 2 * NB2, 256, 0, stream>>>(XL, XH, lc1, hc1, lc2, hc2, G1, G2);
    k_gwm<<<2 * LAYERS * Bn, 256, 0, stream>>>(lw, hw, G1, G2, M);
    k_chain<<<2, 1024, 0, stream>>>(M, lb, lv, lg, lbeta, hb, hv, hg, hbeta, Pcol);
    k_final<<<dim3((Cc * Nn + 255) / 256, Bn), 256, 0, stream>>>(XL, XH, Pcol, alpha, out);
}

// Round 6
// 334.078 us; speedup vs baseline: 4.0990x; 1.1199x over previous
//
#include <hip/hip_runtime.h>

#define Bn 32
#define Cc 128
#define Nn 307
#define Ll 12
#define LH 13
#define LAYERS 4
#define BN_EPS 1e-5f
#define SCW (Cc + 1)  // padded LDS stride to kill bank conflicts

#define NB1 499  // ceil(32*307*13 / 256)
#define NB2 208  // 32*128*13 / 256

// ---- one pass over X: G1[l][b,t0,n] = sum_c X*c1_l ; G2[l][b,t0,c] = sum_n X*c2_l
__global__ __launch_bounds__(256) void k_g12(const float* __restrict__ XL,
                                             const float* __restrict__ XH,
                                             const float* __restrict__ lc1,
                                             const float* __restrict__ hc1,
                                             const float* __restrict__ lc2,
                                             const float* __restrict__ hc2,
                                             float* __restrict__ G1,
                                             float* __restrict__ G2) {
    __shared__ float s_c1[LAYERS * Cc];
    __shared__ float s_c2[LAYERS * Nn];
    int blk = blockIdx.x;
    int tid = threadIdx.x;
    if (blk < 2 * NB1) {
        // ---- G1 part ----
        int ch = blk / NB1;
        const float* X = ch ? XH : XL;
        const float* c1 = ch ? hc1 : lc1;
        int T = ch ? LH : Ll;
        int pad = ch ? 1 : 0;
        for (int j = tid; j < LAYERS * Cc; j += 256) s_c1[j] = c1[j];
        __syncthreads();
        int idx = (blk % NB1) * 256 + tid;
        if (idx >= Bn * Nn * LH) return;
        int t0 = idx % LH;
        int n = (idx / LH) % Nn;
        int b = idx / (LH * Nn);
        if (t0 >= T) return;
        int tsrc = t0 - pad;
        float a0 = 0.f, a1 = 0.f, a2 = 0.f, a3 = 0.f;
        if (tsrc >= 0) {
            const float* p = X + ((size_t)b * Cc * Nn + n) * Ll + tsrc;
            for (int c = 0; c < Cc; ++c) {
                float vx = p[(size_t)c * Nn * Ll];
                a0 += vx * s_c1[0 * Cc + c];
                a1 += vx * s_c1[1 * Cc + c];
                a2 += vx * s_c1[2 * Cc + c];
                a3 += vx * s_c1[3 * Cc + c];
            }
        }
        size_t lstride = (size_t)Bn * LH * Nn;
        size_t base = ((size_t)(ch * LAYERS * Bn + b)) * (LH * Nn) + (size_t)t0 * Nn + n;
        G1[base] = a0;
        G1[base + lstride] = a1;
        G1[base + 2 * lstride] = a2;
        G1[base + 3 * lstride] = a3;
    } else {
        // ---- G2 part ----
        int b2 = blk - 2 * NB1;
        int ch = b2 / NB2;
        const float* X = ch ? XH : XL;
        const float* c2 = ch ? hc2 : lc2;
        int T = ch ? LH : Ll;
        int pad = ch ? 1 : 0;
        for (int j = tid; j < LAYERS * Nn; j += 256) s_c2[j] = c2[j];
        __syncthreads();
        int idx = (b2 % NB2) * 256 + tid;
        int t0 = idx % LH;
        int c = (idx / LH) % Cc;
        int b = idx / (LH * Cc);
        if (t0 >= T) return;
        int tsrc = t0 - pad;
        float a0 = 0.f, a1 = 0.f, a2 = 0.f, a3 = 0.f;
        if (tsrc >= 0) {
            const float* p = X + ((size_t)(b * Cc + c) * Nn) * Ll + tsrc;
            for (int n = 0; n < Nn; ++n) {
                float vx = p[(size_t)n * Ll];
                a0 += vx * s_c2[0 * Nn + n];
                a1 += vx * s_c2[1 * Nn + n];
                a2 += vx * s_c2[2 * Nn + n];
                a3 += vx * s_c2[3 * Nn + n];
            }
        }
        size_t lstride = (size_t)Bn * LH * Cc;
        size_t base = ((size_t)(ch * LAYERS * Bn + b)) * (LH * Cc) + (size_t)t0 * Cc + c;
        G2[base] = a0;
        G2[base + lstride] = a1;
        G2[base + 2 * lstride] = a2;
        G2[base + 3 * lstride] = a3;
    }
}

// ---- per (ch,l,b): GW = G1*w, then M[t0][t1] = sum_c GW*G2 -> global ----
__global__ __launch_bounds__(256) void k_gwm(const float* __restrict__ lw,
                                             const float* __restrict__ hw,
                                             const float* __restrict__ G1,
                                             const float* __restrict__ G2,
                                             float* __restrict__ M) {
    __shared__ float sG1[LH * Nn];
    __shared__ float sAcc[2][LH * SCW];
    __shared__ float sG2[LH * SCW];
    int blk = blockIdx.x;  // (ch*LAYERS + l)*Bn + b
    int cl = blk / Bn;
    int l = cl % LAYERS;
    int ch = cl / LAYERS;
    int T = ch ? LH : Ll;
    const float* w = (ch ? hw : lw) + (size_t)l * Nn * Cc;
    const float* g1 = G1 + (size_t)blk * (LH * Nn);
    const float* g2 = G2 + (size_t)blk * (LH * Cc);
    int tid = threadIdx.x;
    for (int i = tid; i < LH * Nn; i += 256) sG1[i] = (i < T * Nn) ? g1[i] : 0.f;
    for (int i = tid; i < T * Cc; i += 256) sG2[(i / Cc) * SCW + (i % Cc)] = g2[i];
    __syncthreads();
    int half = tid >> 7;
    int c = tid & 127;
    float acc[LH];
#pragma unroll
    for (int t = 0; t < LH; ++t) acc[t] = 0.f;
    int n0 = half ? (Nn / 2) : 0;
    int n1 = half ? Nn : (Nn / 2);
    for (int n = n0; n < n1; ++n) {
        float wv = w[(size_t)n * Cc + c];
#pragma unroll
        for (int t = 0; t < LH; ++t) acc[t] += sG1[t * Nn + n] * wv;
    }
#pragma unroll
    for (int t = 0; t < LH; ++t) sAcc[half][t * SCW + c] = acc[t];
    __syncthreads();
    for (int i = tid; i < LH * Cc; i += 256) {
        int t = i / Cc, cc = i % Cc;
        sAcc[0][t * SCW + cc] += sAcc[1][t * SCW + cc];
    }
    __syncthreads();
    float* Mo = M + (size_t)blk * (LH * LH);
    for (int i = tid; i < T * T; i += 256) {
        int t0 = i / T, t1 = i % T;
        float a = 0.f;
        for (int cc = 0; cc < Cc; ++cc) a += sAcc[0][t0 * SCW + cc] * sG2[t1 * SCW + cc];
        Mo[t0 * LH + t1] = a;
    }
}

// ---- 4-layer chain, compile-time T so all inner loops unroll & LDS reads batch ----
template <int T>
__device__ __forceinline__ void chain_impl(float* __restrict__ sbuf,  // [3][Bn*LH*LH]
                                           float* __restrict__ sMean,
                                           float* __restrict__ sScale,
                                           float* __restrict__ sShift,
                                           const float* __restrict__ M,
                                           const float* __restrict__ bbp,
                                           const float* __restrict__ vp,
                                           const float* __restrict__ gp,
                                           const float* __restrict__ bep,
                                           float* __restrict__ Pcol, int ch) {
    const int TT = T * T;
    const int BUF = Bn * LH * LH;
    int tid = threadIdx.x;
    int ip = 0, ia = 1, ib = 2;
    for (int i = tid; i < Bn * TT; i += 1024) {
        int r = i % TT;
        sbuf[i] = (r / T == r % T) ? 1.f : 0.f;
    }
    __syncthreads();
    for (int l = 0; l < LAYERS; ++l) {
        float* P = sbuf + ip * BUF;
        float* X1 = sbuf + ia * BUF;
        float* X2 = sbuf + ib * BUF;
        const float* Ml = M + ((size_t)(ch * LAYERS + l) * Bn) * (LH * LH);
        const float* bbl = bbp + l * TT;
        const float* vl = vp + l * TT;
        for (int i = tid; i < Bn * LH * LH; i += 1024) X1[i] = Ml[i];  // stage M (stride 13)
        __syncthreads();
        // S1[b][t][t1] = sum_t0 P[b][t0*T+t] * M[b][t0*13+t1] -> X2
        for (int i = tid; i < Bn * TT; i += 1024) {
            int b = i / TT, r = i % TT, t = r / T, t1 = r % T;
            const float* Pb = P + b * TT;
            const float* Mb = X1 + b * LH * LH;
            float a = 0.f;
#pragma unroll
            for (int t0 = 0; t0 < T; ++t0) a += Pb[t0 * T + t] * Mb[t0 * LH + t1];
            X2[i] = a;
        }
        __syncthreads();
        // scores = sigmoid(bb + S1 @ P) -> X1
        for (int i = tid; i < Bn * TT; i += 1024) {
            int b = i / TT, r = i % TT, t = r / T, q = r % T;
            const float* S1b = X2 + b * TT + t * T;
            const float* Pb = P + b * TT;
            float a = bbl[r];
#pragma unroll
            for (int t1 = 0; t1 < T; ++t1) a += S1b[t1] * Pb[t1 * T + q];
            X1[i] = 1.f / (1.f + expf(-a));
        }
        __syncthreads();
        // logits = v @ scores -> X2
        for (int i = tid; i < Bn * TT; i += 1024) {
            int b = i / TT, r = i % TT, t = r / T, q = r % T;
            float a = 0.f;
#pragma unroll
            for (int k = 0; k < T; ++k) a += vl[t * T + k] * X1[b * TT + k * T + q];
            X2[i] = a;
        }
        __syncthreads();
        // BN partials per (q,b) -> X1 (scores dead)
        if (tid < T * Bn) {
            int b = tid % Bn, q = tid / Bn;
            float s = 0.f, ss = 0.f;
#pragma unroll
            for (int t = 0; t < T; ++t) {
                float x = X2[b * TT + t * T + q];
                s += x;
                ss += x * x;
            }
            X1[q * Bn + b] = s;
            X1[T * Bn + q * Bn + b] = ss;
        }
        __syncthreads();
        if (tid < T) {
            float s = 0.f, ss = 0.f;
#pragma unroll 8
            for (int b = 0; b < Bn; ++b) {
                s += X1[tid * Bn + b];
                ss += X1[T * Bn + tid * Bn + b];
            }
            float inv = 1.f / (float)(Bn * T);
            float m = s * inv;
            float var = ss * inv - m * m;
            sMean[tid] = m;
            sScale[tid] = rsqrtf(var + BN_EPS) * gp[l * T + tid];
            sShift[tid] = bep[l * T + tid];
        }
        __syncthreads();
        // softmax rows (b,t) over q -> Co in X1
        if (tid < Bn * T) {
            int b = tid / T, t = tid % T;
            float vals[T];
            float mx = -1e30f;
#pragma unroll
            for (int q = 0; q < T; ++q) {
                float x = (X2[b * TT + t * T + q] - sMean[q]) * sScale[q] + sShift[q];
                vals[q] = x;
                mx = fmaxf(mx, x);
            }
            float sm = 0.f;
#pragma unroll
            for (int q = 0; q < T; ++q) {
                vals[q] = expf(vals[q] - mx);
                sm += vals[q];
            }
            float inv = 1.f / sm;
#pragma unroll
            for (int q = 0; q < T; ++q) X1[b * TT + t * T + q] = vals[q] * inv;
        }
        __syncthreads();
        // Pn[b][t0][q] = sum_t P[b][t0*T+t] * Co[b][q*T+t] -> X2
        for (int i = tid; i < Bn * TT; i += 1024) {
            int b = i / TT, r = i % TT, t0 = r / T, q = r % T;
            const float* Pb = P + b * TT;
            const float* Cb = X1 + b * TT + q * T;
            float a = 0.f;
#pragma unroll
            for (int t = 0; t < T; ++t) a += Pb[t0 * T + t] * Cb[t];
            X2[i] = a;
        }
        __syncthreads();
        int tmp = ip; ip = ib; ib = tmp;
    }
    const float* Pf = sbuf + ip * BUF;
    for (int i = tid; i < Bn * T; i += 1024) {
        int b = i / T, t0 = i % T;
        Pcol[ch * Bn * LH + b * LH + t0] = Pf[b * TT + t0 * T + (T - 1)];
    }
}

__global__ __launch_bounds__(1024) void k_chain(const float* __restrict__ M,
                                                const float* __restrict__ lb,
                                                const float* __restrict__ lv,
                                                const float* __restrict__ lg,
                                                const float* __restrict__ lbe,
                                                const float* __restrict__ hb,
                                                const float* __restrict__ hv,
                                                const float* __restrict__ hg,
                                                const float* __restrict__ hbe,
                                                float* __restrict__ Pcol) {
    __shared__ float sbuf[3 * Bn * LH * LH];
    __shared__ float sMean[LH], sScale[LH], sShift[LH];
    int ch = blockIdx.x;
    if (ch == 0)
        chain_impl<Ll>(sbuf, sMean, sScale, sShift, M, lb, lv, lg, lbe, Pcol, 0);
    else
        chain_impl<LH>(sbuf, sMean, sScale, sShift, M, hb, hv, hg, hbe, Pcol, 1);
}

// ---- final: residuals + alpha blend using last-column weights ----
__global__ __launch_bounds__(256) void k_final(const float* __restrict__ XL,
                                               const float* __restrict__ XH,
                                               const float* __restrict__ Pcol,
                                               const float* __restrict__ alpha,
                                               float* __restrict__ out) {
    __shared__ float s_pl[Ll];
    __shared__ float s_ph[LH];
    int b = blockIdx.y;
    int tid = threadIdx.x;
    if (tid < Ll) s_pl[tid] = Pcol[b * LH + tid];
    if (tid < LH) s_ph[tid] = Pcol[Bn * LH + b * LH + tid];
    __syncthreads();
    int cn = blockIdx.x * blockDim.x + tid;
    if (cn >= Cc * Nn) return;
    size_t idx = (size_t)b * Cc * Nn + cn;
    const float* pl = XL + idx * Ll;
    const float* ph = XH + idx * Ll;
    float accL = 0.f, accH = 0.f;
#pragma unroll
    for (int t = 0; t < Ll; ++t) {
        accL += pl[t] * s_pl[t];
        accH += ph[t] * s_ph[t + 1];  // high-channel t0=0 plane is the zero pad
    }
    float a = 1.f / (1.f + expf(-alpha[0]));
    float xl = pl[Ll - 1] + accL;
    float xh = ph[Ll - 1] + accH;
    out[idx] = a * xl + (1.f - a) * xh;
}

extern "C" void kernel_launch(void* const* d_in, const int* in_sizes, int n_in,
                              void* d_out, int out_size, void* d_ws, size_t ws_size,
                              hipStream_t stream) {
    const float* XL = (const float*)d_in[0];
    const float* XH = (const float*)d_in[1];
    const float* lc1 = (const float*)d_in[2];
    const float* lc2 = (const float*)d_in[3];
    const float* lw = (const float*)d_in[4];
    const float* lb = (const float*)d_in[5];
    const float* lv = (const float*)d_in[6];
    const float* lg = (const float*)d_in[7];
    const float* lbeta = (const float*)d_in[8];
    const float* hc1 = (const float*)d_in[9];
    const float* hc2 = (const float*)d_in[10];
    const float* hw = (const float*)d_in[11];
    const float* hb = (const float*)d_in[12];
    const float* hv = (const float*)d_in[13];
    const float* hg = (const float*)d_in[14];
    const float* hbeta = (const float*)d_in[15];
    const float* alpha = (const float*)d_in[16];
    float* out = (float*)d_out;

    float* ws = (float*)d_ws;
    float* G1 = ws;
    float* G2 = G1 + (size_t)2 * LAYERS * Bn * LH * Nn;
    float* M = G2 + (size_t)2 * LAYERS * Bn * LH * Cc;
    float* Pcol = M + (size_t)2 * LAYERS * Bn * LH * LH;

    k_g12<<<2 * NB1 + 2 * NB2, 256, 0, stream>>>(XL, XH, lc1, hc1, lc2, hc2, G1, G2);
    k_gwm<<<2 * LAYERS * Bn, 256, 0, stream>>>(lw, hw, G1, G2, M);
    k_chain<<<2, 1024, 0, stream>>>(M, lb, lv, lg, lbeta, hb, hv, hg, hbeta, Pcol);
    k_final<<<dim3((Cc * Nn + 255) / 256, Bn), 256, 0, stream>>>(XL, XH, Pcol, alpha, out);
}